// Round 1
// baseline (395.702 us; speedup 1.0000x reference)
//
#include <hip/hip_runtime.h>
#include <hip/hip_bf16.h>

#define B_DIM 2048
#define S_DIM 32768
#define G_DIM 4096
#define E_DIM 1024

typedef __bf16 bf16x8 __attribute__((ext_vector_type(8)));
typedef float f32x4 __attribute__((ext_vector_type(4)));

__device__ __forceinline__ unsigned short f2bf(float f) {
  unsigned int u = __builtin_bit_cast(unsigned int, f);
  u += 0x7FFFu + ((u >> 16) & 1u);   // round-to-nearest-even (no NaN inputs here)
  return (unsigned short)(u >> 16);
}

__device__ __forceinline__ void async16(void* lds, const void* g) {
  __builtin_amdgcn_global_load_lds(
      (const __attribute__((address_space(1))) unsigned int*)g,
      (__attribute__((address_space(3))) unsigned int*)lds, 16, 0, 0);
}

// ---------------- setup: invert permutation, build per-column meta ----------
// For position s in permuted order: original column c = perm[s], group
// g = segment_ids[s], a = agg_type[g].  Column c contributes to y[:, g] as:
//   a==0: x          -> cmul = 1
//   a==2: w_elem*x   -> cmul = w_elem[s]
//   a==1: (x!=0)     -> cmul = 0, or_flag set
__global__ __launch_bounds__(256) void setup_meta(
    const float* __restrict__ w_elem, const int* __restrict__ perm,
    const int* __restrict__ segid, const int* __restrict__ agg,
    unsigned short* __restrict__ meta, float* __restrict__ cmul) {
  int s = blockIdx.x * 256 + threadIdx.x;
  if (s >= S_DIM) return;
  int c = perm[s];
  int g = segid[s];
  int a = agg[g];
  meta[c] = (unsigned short)(g | (a == 1 ? 0x1000 : 0));
  cmul[c] = (a == 0) ? 1.0f : (a == 2 ? w_elem[s] : 0.0f);
}

// ---------------- W (f32, [E][G]) -> bf16 ----------------
__global__ __launch_bounds__(256) void conv_w(const float* __restrict__ W,
                                              unsigned short* __restrict__ Wb) {
  size_t i = ((size_t)blockIdx.x * 256 + threadIdx.x) * 4;
  float4 v = *reinterpret_cast<const float4*>(W + i);
  ushort4 o;
  o.x = f2bf(v.x);
  o.y = f2bf(v.y);
  o.z = f2bf(v.z);
  o.w = f2bf(v.w);
  *reinterpret_cast<ushort4*>(Wb + i) = o;
}

// ---------------- stage 1: per-row segment reduce into LDS histogram -------
// One block per row b. Coalesced float4 stream of x[b,:], LDS atomic adds
// into acc[group]. Finalize: OR-clamp for a==1 groups, relu, cast to bf16.
__global__ __launch_bounds__(256) void seg_reduce(
    const float* __restrict__ x, const unsigned short* __restrict__ meta,
    const float* __restrict__ cmul, const int* __restrict__ agg,
    unsigned short* __restrict__ y) {
  __shared__ float acc[G_DIM];  // 16 KB
  const int t = threadIdx.x;
  const int b = blockIdx.x;
  for (int g = t; g < G_DIM; g += 256) acc[g] = 0.0f;
  __syncthreads();

  const float4* xr = reinterpret_cast<const float4*>(x + (size_t)b * S_DIM);
  const ushort4* mr = reinterpret_cast<const ushort4*>(meta);
  const float4* cr = reinterpret_cast<const float4*>(cmul);

  for (int i = t; i < S_DIM / 4; i += 256) {
    float4 xv = xr[i];
    ushort4 mv = mr[i];
    float4 cv = cr[i];
    float v0 = xv.x * cv.x + (((mv.x & 0x1000) && xv.x != 0.0f) ? 1.0f : 0.0f);
    atomicAdd(&acc[mv.x & 0xFFF], v0);
    float v1 = xv.y * cv.y + (((mv.y & 0x1000) && xv.y != 0.0f) ? 1.0f : 0.0f);
    atomicAdd(&acc[mv.y & 0xFFF], v1);
    float v2 = xv.z * cv.z + (((mv.z & 0x1000) && xv.z != 0.0f) ? 1.0f : 0.0f);
    atomicAdd(&acc[mv.z & 0xFFF], v2);
    float v3 = xv.w * cv.w + (((mv.w & 0x1000) && xv.w != 0.0f) ? 1.0f : 0.0f);
    atomicAdd(&acc[mv.w & 0xFFF], v3);
  }
  __syncthreads();

  for (int g = t; g < G_DIM; g += 256) {
    float v = acc[g];
    if (agg[g] == 1) v = (v > 0.0f) ? 1.0f : 0.0f;  // acc holds nnz count
    v = fmaxf(v, 0.0f);                              // relu
    y[(size_t)b * G_DIM + g] = f2bf(v);
  }
}

// ---------------- stage 2: out[b,e] = sum_g yr[b,g] * W[e,g]  (bf16 MFMA) --
// Both operands K-contiguous ("B^T" layout). 64x64 tile, BK=64, 4 waves in
// 2x2, each wave a 32x32 output (2x2 fragments of 16x16x32).
// LDS layout XOR-swizzled in 16B slots: elem (row,k) at byte
//   row*128 + ((k/8) ^ (row&7))*16 + (k%8)*2
// global_load_lds writes linearly (byte t*16), so the global SOURCE address
// is inverse-swizzled (rule: linear dest + pre-swizzled source + swz read).
__global__ __launch_bounds__(256) void gemm_bt(
    const unsigned short* __restrict__ A,   // y bf16 [B_DIM][G_DIM]
    const unsigned short* __restrict__ Bw,  // W bf16 [E_DIM][G_DIM]
    float* __restrict__ C) {                // out f32 [B_DIM][E_DIM]
  __shared__ __align__(16) unsigned short As[64 * 64];  // 8 KB
  __shared__ __align__(16) unsigned short Bs[64 * 64];  // 8 KB
  const int t = threadIdx.x;
  const int lane = t & 63;
  const int wid = t >> 6;
  const int wr = wid >> 1;  // wave row (M)
  const int wc = wid & 1;   // wave col (N)
  const int row0 = blockIdx.y * 64;
  const int col0 = blockIdx.x * 64;

  // staging: thread t covers LDS byte t*16 -> (row=t>>3, slot=t&7)
  const int r_ = t >> 3;  // 0..31
  const int s_ = t & 7;
  const int ksw = (s_ ^ (r_ & 7)) * 8;  // inverse-swizzled k offset (elements)
  const unsigned short* Ag0 = A + (size_t)(row0 + r_) * G_DIM + ksw;
  const unsigned short* Ag1 = A + (size_t)(row0 + r_ + 32) * G_DIM + ksw;
  const unsigned short* Bg0 = Bw + (size_t)(col0 + r_) * G_DIM + ksw;
  const unsigned short* Bg1 = Bw + (size_t)(col0 + r_ + 32) * G_DIM + ksw;

  char* AsB = (char*)As;
  char* BsB = (char*)Bs;
  char* dA0 = AsB + wid * 1024;          // wave-uniform LDS dst bases
  char* dA1 = AsB + 4096 + wid * 1024;
  char* dB0 = BsB + wid * 1024;
  char* dB1 = BsB + 4096 + wid * 1024;

  const int lm = lane & 15;
  const int lk = lane >> 4;  // 0..3

  f32x4 acc[2][2] = {};

  for (int kt = 0; kt < G_DIM; kt += 64) {
    async16(dA0, Ag0 + kt);
    async16(dA1, Ag1 + kt);
    async16(dB0, Bg0 + kt);
    async16(dB1, Bg1 + kt);
    __syncthreads();  // drains vmcnt before barrier
#pragma unroll
    for (int kk = 0; kk < 2; ++kk) {
      bf16x8 af[2], bfr[2];
#pragma unroll
      for (int m = 0; m < 2; ++m) {
        int row = wr * 32 + m * 16 + lm;
        int slot = (kk * 4 + lk) ^ (row & 7);
        af[m] = *(const bf16x8*)(AsB + row * 128 + slot * 16);
      }
#pragma unroll
      for (int n = 0; n < 2; ++n) {
        int row = wc * 32 + n * 16 + lm;
        int slot = (kk * 4 + lk) ^ (row & 7);
        bfr[n] = *(const bf16x8*)(BsB + row * 128 + slot * 16);
      }
#pragma unroll
      for (int m = 0; m < 2; ++m)
#pragma unroll
        for (int n = 0; n < 2; ++n)
          acc[m][n] = __builtin_amdgcn_mfma_f32_16x16x32_bf16(af[m], bfr[n],
                                                              acc[m][n], 0, 0, 0);
    }
    __syncthreads();  // protect LDS before next stage
  }

  // C/D layout: col = lane&15, row = (lane>>4)*4 + reg
#pragma unroll
  for (int m = 0; m < 2; ++m) {
    int r = row0 + wr * 32 + m * 16 + lk * 4;
#pragma unroll
    for (int n = 0; n < 2; ++n) {
      int c = col0 + wc * 32 + n * 16 + lm;
#pragma unroll
      for (int q = 0; q < 4; ++q) {
        C[(size_t)(r + q) * E_DIM + c] = acc[m][n][q];
      }
    }
  }
}

extern "C" void kernel_launch(void* const* d_in, const int* in_sizes, int n_in,
                              void* d_out, int out_size, void* d_ws, size_t ws_size,
                              hipStream_t stream) {
  const float* x = (const float*)d_in[0];
  const float* W = (const float*)d_in[1];
  const float* w_elem = (const float*)d_in[2];
  const int* perm = (const int*)d_in[3];
  const int* segid = (const int*)d_in[4];
  const int* agg = (const int*)d_in[5];
  float* out = (float*)d_out;

  char* ws = (char*)d_ws;
  unsigned short* y = (unsigned short*)ws;  // B*G bf16 = 16 MB
  unsigned short* Wb =
      (unsigned short*)(ws + (size_t)B_DIM * G_DIM * 2);  // E*G bf16 = 8 MB
  unsigned short* meta =
      (unsigned short*)(ws + (size_t)B_DIM * G_DIM * 2 + (size_t)E_DIM * G_DIM * 2);
  float* cmul = (float*)((char*)meta + (size_t)S_DIM * 2);

  hipLaunchKernelGGL(setup_meta, dim3(S_DIM / 256), dim3(256), 0, stream,
                     w_elem, perm, segid, agg, meta, cmul);
  hipLaunchKernelGGL(conv_w, dim3((E_DIM * G_DIM / 4) / 256), dim3(256), 0,
                     stream, W, Wb);
  hipLaunchKernelGGL(seg_reduce, dim3(B_DIM), dim3(256), 0, stream, x, meta,
                     cmul, agg, y);
  hipLaunchKernelGGL(gemm_bt, dim3(E_DIM / 64, B_DIM / 64), dim3(256), 0,
                     stream, y, Wb, out);
}

// Round 3
// 392.017 us; speedup vs baseline: 1.0094x; 1.0094x over previous
//
#include <hip/hip_runtime.h>
#include <hip/hip_bf16.h>

#define B_DIM 2048
#define S_DIM 32768
#define G_DIM 4096
#define E_DIM 1024

typedef __bf16 bf16x8 __attribute__((ext_vector_type(8)));
typedef float f32x4 __attribute__((ext_vector_type(4)));

__device__ __forceinline__ unsigned short f2bf(float f) {
  unsigned int u = __builtin_bit_cast(unsigned int, f);
  u += 0x7FFFu + ((u >> 16) & 1u);   // round-to-nearest-even (no NaN inputs here)
  return (unsigned short)(u >> 16);
}

__device__ __forceinline__ void async16(void* lds, const void* g) {
  __builtin_amdgcn_global_load_lds(
      (const __attribute__((address_space(1))) unsigned int*)g,
      (__attribute__((address_space(3))) unsigned int*)lds, 16, 0, 0);
}

// Non-returning LDS float atomic add — guarantees ds_add_f32 (no rtn, no
// per-op waitcnt). NOTE: these DS ops are invisible to SIInsertWaitcnts, so
// __syncthreads() alone may NOT drain them before s_barrier — every use must
// be followed (before the barrier) by an explicit s_waitcnt lgkmcnt(0).
__device__ __forceinline__ void lds_add(float* p, float v) {
  unsigned off = (unsigned)(size_t)(__attribute__((address_space(3))) float*)p;
  asm volatile("ds_add_f32 %0, %1" :: "v"(off), "v"(v));
}

// ---------------- setup: invert permutation, build per-column meta ----------
__global__ __launch_bounds__(256) void setup_meta(
    const float* __restrict__ w_elem, const int* __restrict__ perm,
    const int* __restrict__ segid, const int* __restrict__ agg,
    unsigned short* __restrict__ meta, float* __restrict__ cmul) {
  int s = blockIdx.x * 256 + threadIdx.x;
  if (s >= S_DIM) return;
  int c = perm[s];
  int g = segid[s];
  int a = agg[g];
  meta[c] = (unsigned short)(g | (a == 1 ? 0x1000 : 0));
  cmul[c] = (a == 0) ? 1.0f : (a == 2 ? w_elem[s] : 0.0f);
}

// ---------------- W (f32, [E][G]) -> bf16 ----------------
__global__ __launch_bounds__(256) void conv_w(const float* __restrict__ W,
                                              unsigned short* __restrict__ Wb) {
  size_t i = ((size_t)blockIdx.x * 256 + threadIdx.x) * 4;
  float4 v = *reinterpret_cast<const float4*>(W + i);
  ushort4 o;
  o.x = f2bf(v.x);
  o.y = f2bf(v.y);
  o.z = f2bf(v.z);
  o.w = f2bf(v.w);
  *reinterpret_cast<ushort4*>(Wb + i) = o;
}

// ---------------- stage 1: per-row segment reduce into LDS histogram -------
// One block per row b. Two coalesced float4 streams (8 elems/thread/iter),
// ds_add_f32 scatter into acc[4096].
__global__ __launch_bounds__(256, 8) void seg_reduce(
    const float* __restrict__ x, const unsigned short* __restrict__ meta,
    const float* __restrict__ cmul, const int* __restrict__ agg,
    unsigned short* __restrict__ y) {
  __shared__ float acc[G_DIM];  // 16 KB
  const int t = threadIdx.x;
  const int b = blockIdx.x;
  for (int g = t; g < G_DIM; g += 256) acc[g] = 0.0f;
  __syncthreads();

  const float4* xr = reinterpret_cast<const float4*>(x + (size_t)b * S_DIM);
  const ushort4* mr = reinterpret_cast<const ushort4*>(meta);
  const float4* cr = reinterpret_cast<const float4*>(cmul);

#pragma unroll 2
  for (int i = 0; i < S_DIM / 4 / 512; ++i) {
    int i0 = i * 512 + t;
    int i1 = i0 + 256;
    float4 xv0 = xr[i0];
    ushort4 mv0 = mr[i0];
    float4 cv0 = cr[i0];
    float4 xv1 = xr[i1];
    ushort4 mv1 = mr[i1];
    float4 cv1 = cr[i1];

    lds_add(&acc[mv0.x & 0xFFF],
            xv0.x * cv0.x + (((mv0.x & 0x1000) && xv0.x != 0.0f) ? 1.0f : 0.0f));
    lds_add(&acc[mv0.y & 0xFFF],
            xv0.y * cv0.y + (((mv0.y & 0x1000) && xv0.y != 0.0f) ? 1.0f : 0.0f));
    lds_add(&acc[mv0.z & 0xFFF],
            xv0.z * cv0.z + (((mv0.z & 0x1000) && xv0.z != 0.0f) ? 1.0f : 0.0f));
    lds_add(&acc[mv0.w & 0xFFF],
            xv0.w * cv0.w + (((mv0.w & 0x1000) && xv0.w != 0.0f) ? 1.0f : 0.0f));
    lds_add(&acc[mv1.x & 0xFFF],
            xv1.x * cv1.x + (((mv1.x & 0x1000) && xv1.x != 0.0f) ? 1.0f : 0.0f));
    lds_add(&acc[mv1.y & 0xFFF],
            xv1.y * cv1.y + (((mv1.y & 0x1000) && xv1.y != 0.0f) ? 1.0f : 0.0f));
    lds_add(&acc[mv1.z & 0xFFF],
            xv1.z * cv1.z + (((mv1.z & 0x1000) && xv1.z != 0.0f) ? 1.0f : 0.0f));
    lds_add(&acc[mv1.w & 0xFFF],
            xv1.w * cv1.w + (((mv1.w & 0x1000) && xv1.w != 0.0f) ? 1.0f : 0.0f));
  }
  // Drain OUR asm ds_adds (invisible to the compiler's waitcnt model) before
  // the barrier — this is the round-2 correctness fix.
  asm volatile("s_waitcnt lgkmcnt(0)" ::: "memory");
  __syncthreads();

  for (int g = t; g < G_DIM; g += 256) {
    float v = acc[g];
    if (agg[g] == 1) v = (v > 0.0f) ? 1.0f : 0.0f;  // acc holds nnz count
    v = fmaxf(v, 0.0f);                              // relu
    y[(size_t)b * G_DIM + g] = f2bf(v);
  }
}

// ---------------- stage 2: out[b,e] = sum_g yr[b,g] * W[e,g]  (bf16 MFMA) --
__global__ __launch_bounds__(256) void gemm_bt(
    const unsigned short* __restrict__ A,   // y bf16 [B_DIM][G_DIM]
    const unsigned short* __restrict__ Bw,  // W bf16 [E_DIM][G_DIM]
    float* __restrict__ C) {                // out f32 [B_DIM][E_DIM]
  __shared__ __align__(16) unsigned short As[64 * 64];  // 8 KB
  __shared__ __align__(16) unsigned short Bs[64 * 64];  // 8 KB
  const int t = threadIdx.x;
  const int lane = t & 63;
  const int wid = t >> 6;
  const int wr = wid >> 1;  // wave row (M)
  const int wc = wid & 1;   // wave col (N)
  const int row0 = blockIdx.y * 64;
  const int col0 = blockIdx.x * 64;

  // staging: thread t covers LDS byte t*16 -> (row=t>>3, slot=t&7)
  const int r_ = t >> 3;  // 0..31
  const int s_ = t & 7;
  const int ksw = (s_ ^ (r_ & 7)) * 8;  // inverse-swizzled k offset (elements)
  const unsigned short* Ag0 = A + (size_t)(row0 + r_) * G_DIM + ksw;
  const unsigned short* Ag1 = A + (size_t)(row0 + r_ + 32) * G_DIM + ksw;
  const unsigned short* Bg0 = Bw + (size_t)(col0 + r_) * G_DIM + ksw;
  const unsigned short* Bg1 = Bw + (size_t)(col0 + r_ + 32) * G_DIM + ksw;

  char* AsB = (char*)As;
  char* BsB = (char*)Bs;
  char* dA0 = AsB + wid * 1024;          // wave-uniform LDS dst bases
  char* dA1 = AsB + 4096 + wid * 1024;
  char* dB0 = BsB + wid * 1024;
  char* dB1 = BsB + 4096 + wid * 1024;

  const int lm = lane & 15;
  const int lk = lane >> 4;  // 0..3

  f32x4 acc[2][2] = {};

  for (int kt = 0; kt < G_DIM; kt += 64) {
    async16(dA0, Ag0 + kt);
    async16(dA1, Ag1 + kt);
    async16(dB0, Bg0 + kt);
    async16(dB1, Bg1 + kt);
    __syncthreads();  // drains vmcnt before barrier
#pragma unroll
    for (int kk = 0; kk < 2; ++kk) {
      bf16x8 af[2], bfr[2];
#pragma unroll
      for (int m = 0; m < 2; ++m) {
        int row = wr * 32 + m * 16 + lm;
        int slot = (kk * 4 + lk) ^ (row & 7);
        af[m] = *(const bf16x8*)(AsB + row * 128 + slot * 16);
      }
#pragma unroll
      for (int n = 0; n < 2; ++n) {
        int row = wc * 32 + n * 16 + lm;
        int slot = (kk * 4 + lk) ^ (row & 7);
        bfr[n] = *(const bf16x8*)(BsB + row * 128 + slot * 16);
      }
#pragma unroll
      for (int m = 0; m < 2; ++m)
#pragma unroll
        for (int n = 0; n < 2; ++n)
          acc[m][n] = __builtin_amdgcn_mfma_f32_16x16x32_bf16(af[m], bfr[n],
                                                              acc[m][n], 0, 0, 0);
    }
    __syncthreads();  // protect LDS before next stage
  }

  // C/D layout: col = lane&15, row = (lane>>4)*4 + reg
#pragma unroll
  for (int m = 0; m < 2; ++m) {
    int r = row0 + wr * 32 + m * 16 + lk * 4;
#pragma unroll
    for (int n = 0; n < 2; ++n) {
      int c = col0 + wc * 32 + n * 16 + lm;
#pragma unroll
      for (int q = 0; q < 4; ++q) {
        C[(size_t)(r + q) * E_DIM + c] = acc[m][n][q];
      }
    }
  }
}

extern "C" void kernel_launch(void* const* d_in, const int* in_sizes, int n_in,
                              void* d_out, int out_size, void* d_ws, size_t ws_size,
                              hipStream_t stream) {
  const float* x = (const float*)d_in[0];
  const float* W = (const float*)d_in[1];
  const float* w_elem = (const float*)d_in[2];
  const int* perm = (const int*)d_in[3];
  const int* segid = (const int*)d_in[4];
  const int* agg = (const int*)d_in[5];
  float* out = (float*)d_out;

  char* ws = (char*)d_ws;
  unsigned short* y = (unsigned short*)ws;  // B*G bf16 = 16 MB
  unsigned short* Wb =
      (unsigned short*)(ws + (size_t)B_DIM * G_DIM * 2);  // E*G bf16 = 8 MB
  unsigned short* meta =
      (unsigned short*)(ws + (size_t)B_DIM * G_DIM * 2 + (size_t)E_DIM * G_DIM * 2);
  float* cmul = (float*)((char*)meta + (size_t)S_DIM * 2);

  hipLaunchKernelGGL(setup_meta, dim3(S_DIM / 256), dim3(256), 0, stream,
                     w_elem, perm, segid, agg, meta, cmul);
  hipLaunchKernelGGL(conv_w, dim3((E_DIM * G_DIM / 4) / 256), dim3(256), 0,
                     stream, W, Wb);
  hipLaunchKernelGGL(seg_reduce, dim3(B_DIM), dim3(256), 0, stream, x, meta,
                     cmul, agg, y);
  hipLaunchKernelGGL(gemm_bt, dim3(E_DIM / 64, B_DIM / 64), dim3(256), 0,
                     stream, y, Wb, out);
}

// Round 4
// 224.443 us; speedup vs baseline: 1.7630x; 1.7466x over previous
//
#include <hip/hip_runtime.h>
#include <hip/hip_bf16.h>

#define B_DIM 2048
#define S_DIM 32768
#define G_DIM 4096
#define E_DIM 1024

typedef __bf16 bf16x8 __attribute__((ext_vector_type(8)));
typedef float f32x4 __attribute__((ext_vector_type(4)));
typedef unsigned short ushort8 __attribute__((ext_vector_type(8)));

__device__ __forceinline__ unsigned short f2bf(float f) {
  unsigned int u = __builtin_bit_cast(unsigned int, f);
  u += 0x7FFFu + ((u >> 16) & 1u);   // round-to-nearest-even (no NaN inputs here)
  return (unsigned short)(u >> 16);
}

__device__ __forceinline__ void async16(void* lds, const void* g) {
  __builtin_amdgcn_global_load_lds(
      (const __attribute__((address_space(1))) unsigned int*)g,
      (__attribute__((address_space(3))) unsigned int*)lds, 16, 0, 0);
}

// Non-returning LDS float atomic add (ds_add_f32). Invisible to the
// compiler's waitcnt model: must be drained with an explicit
// s_waitcnt lgkmcnt(0) before any barrier that readers wait on.
__device__ __forceinline__ void lds_add(float* p, float v) {
  unsigned off = (unsigned)(size_t)(__attribute__((address_space(3))) float*)p;
  asm volatile("ds_add_f32 %0, %1" :: "v"(off), "v"(v));
}

// ---------------- setup: s-ordered meta (no scatter) ------------------------
// pcol[s] = perm[s] | (or_flag << 15)   (perm < 32768 fits 15 bits)
// cm_s[s] = multiplier: a==0 -> 1, a==2 -> w_elem[s], a==1 -> 0 (flag used)
__global__ __launch_bounds__(256) void setup_meta(
    const float* __restrict__ w_elem, const int* __restrict__ perm,
    const int* __restrict__ segid, const int* __restrict__ agg,
    unsigned short* __restrict__ pcol, float* __restrict__ cm_s) {
  int s = blockIdx.x * 256 + threadIdx.x;
  if (s >= S_DIM) return;
  int g = segid[s];
  int a = agg[g];
  pcol[s] = (unsigned short)(perm[s] | (a == 1 ? 0x8000 : 0));
  cm_s[s] = (a == 0) ? 1.0f : (a == 2 ? w_elem[s] : 0.0f);
}

// ---------------- W (f32, [E][G]) -> bf16 ----------------
__global__ __launch_bounds__(256) void conv_w(const float* __restrict__ W,
                                              unsigned short* __restrict__ Wb) {
  size_t i = ((size_t)blockIdx.x * 256 + threadIdx.x) * 4;
  float4 v = *reinterpret_cast<const float4*>(W + i);
  ushort4 o;
  o.x = f2bf(v.x);
  o.y = f2bf(v.y);
  o.z = f2bf(v.z);
  o.w = f2bf(v.w);
  *reinterpret_cast<ushort4*>(Wb + i) = o;
}

// ---------------- stage 1: row-in-LDS segment reduce, run-combined ---------
// One block per row b, 1024 threads. Full row staged in LDS (128 KB) via
// global_load_lds; each thread walks 32 consecutive s-positions (segment_ids
// sorted => contiguous group runs, avg len 8), combines each run in-register,
// and flushes once per run: plain ds_write for interior (exclusive) runs,
// ds_add_f32 only for the <=2 range-boundary runs. ~16x fewer atomic lanes
// than element-wise scatter (the R1-R3 3.1 cyc/lane atomic floor).
__global__ __launch_bounds__(1024, 1) void seg_reduce(
    const float* __restrict__ x, const unsigned short* __restrict__ pcol,
    const float* __restrict__ cm_s, const int* __restrict__ segid,
    const int* __restrict__ agg, unsigned short* __restrict__ y) {
  __shared__ float xrow[S_DIM];  // 128 KB
  __shared__ float acc[G_DIM];   // 16 KB
  const int t = threadIdx.x;
  const int b = blockIdx.x;

#pragma unroll
  for (int i = 0; i < G_DIM / 1024; ++i) acc[t + i * 1024] = 0.0f;

  // stage full row, linear copy (8 x 16B per thread)
  const char* xg = (const char*)(x + (size_t)b * S_DIM);
#pragma unroll
  for (int i = 0; i < (S_DIM * 4) / (1024 * 16); ++i) {
    int off = i * (1024 * 16) + t * 16;
    async16((char*)xrow + off, xg + off);
  }
  __syncthreads();  // drains vmcnt (builtin is tracked) + acc zero visible

  const int s0 = t * 32;
  float sum = 0.0f;
  int gprev = segid[s0];
  int nflush = 0;

#pragma unroll
  for (int c = 0; c < 4; ++c) {
    int sb = s0 + c * 8;
    ushort8 pc = *reinterpret_cast<const ushort8*>(pcol + sb);
    float4 cm0 = *reinterpret_cast<const float4*>(cm_s + sb);
    float4 cm1 = *reinterpret_cast<const float4*>(cm_s + sb + 4);
    int4 g0 = *reinterpret_cast<const int4*>(segid + sb);
    int4 g1 = *reinterpret_cast<const int4*>(segid + sb + 4);
    float xv[8];
#pragma unroll
    for (int j = 0; j < 8; ++j) xv[j] = xrow[pc[j] & 0x7FFF];
    float cmv[8] = {cm0.x, cm0.y, cm0.z, cm0.w, cm1.x, cm1.y, cm1.z, cm1.w};
    int gv[8] = {g0.x, g0.y, g0.z, g0.w, g1.x, g1.y, g1.z, g1.w};
#pragma unroll
    for (int j = 0; j < 8; ++j) {
      float v = (pc[j] & 0x8000) ? (xv[j] != 0.0f ? 1.0f : 0.0f)
                                 : xv[j] * cmv[j];
      int g = gv[j];
      if (g != gprev) {
        // run ended inside my range
        if (nflush == 0) {
          lds_add(&acc[gprev], sum);  // first run may extend into prev thread
        } else {
          acc[gprev] = sum;  // interior run: exclusively mine
        }
        ++nflush;
        sum = 0.0f;
        gprev = g;
      }
      sum += v;
    }
  }
  lds_add(&acc[gprev], sum);  // last run may extend into next thread

  // Drain asm ds_adds (invisible to compiler waitcnt model) before barrier.
  asm volatile("s_waitcnt lgkmcnt(0)" ::: "memory");
  __syncthreads();

#pragma unroll
  for (int i = 0; i < G_DIM / 1024; ++i) {
    int g = t + i * 1024;
    float v = acc[g];
    if (agg[g] == 1) v = (v > 0.0f) ? 1.0f : 0.0f;  // acc holds nnz count
    v = fmaxf(v, 0.0f);                              // relu
    y[(size_t)b * G_DIM + g] = f2bf(v);
  }
}

// ---------------- stage 2: out[b,e] = sum_g yr[b,g] * W[e,g]  (bf16 MFMA) --
__global__ __launch_bounds__(256) void gemm_bt(
    const unsigned short* __restrict__ A,   // y bf16 [B_DIM][G_DIM]
    const unsigned short* __restrict__ Bw,  // W bf16 [E_DIM][G_DIM]
    float* __restrict__ C) {                // out f32 [B_DIM][E_DIM]
  __shared__ __align__(16) unsigned short As[64 * 64];  // 8 KB
  __shared__ __align__(16) unsigned short Bs[64 * 64];  // 8 KB
  const int t = threadIdx.x;
  const int lane = t & 63;
  const int wid = t >> 6;
  const int wr = wid >> 1;  // wave row (M)
  const int wc = wid & 1;   // wave col (N)
  const int row0 = blockIdx.y * 64;
  const int col0 = blockIdx.x * 64;

  // staging: thread t covers LDS byte t*16 -> (row=t>>3, slot=t&7)
  const int r_ = t >> 3;  // 0..31
  const int s_ = t & 7;
  const int ksw = (s_ ^ (r_ & 7)) * 8;  // inverse-swizzled k offset (elements)
  const unsigned short* Ag0 = A + (size_t)(row0 + r_) * G_DIM + ksw;
  const unsigned short* Ag1 = A + (size_t)(row0 + r_ + 32) * G_DIM + ksw;
  const unsigned short* Bg0 = Bw + (size_t)(col0 + r_) * G_DIM + ksw;
  const unsigned short* Bg1 = Bw + (size_t)(col0 + r_ + 32) * G_DIM + ksw;

  char* AsB = (char*)As;
  char* BsB = (char*)Bs;
  char* dA0 = AsB + wid * 1024;          // wave-uniform LDS dst bases
  char* dA1 = AsB + 4096 + wid * 1024;
  char* dB0 = BsB + wid * 1024;
  char* dB1 = BsB + 4096 + wid * 1024;

  const int lm = lane & 15;
  const int lk = lane >> 4;  // 0..3

  f32x4 acc[2][2] = {};

  for (int kt = 0; kt < G_DIM; kt += 64) {
    async16(dA0, Ag0 + kt);
    async16(dA1, Ag1 + kt);
    async16(dB0, Bg0 + kt);
    async16(dB1, Bg1 + kt);
    __syncthreads();  // drains vmcnt before barrier
#pragma unroll
    for (int kk = 0; kk < 2; ++kk) {
      bf16x8 af[2], bfr[2];
#pragma unroll
      for (int m = 0; m < 2; ++m) {
        int row = wr * 32 + m * 16 + lm;
        int slot = (kk * 4 + lk) ^ (row & 7);
        af[m] = *(const bf16x8*)(AsB + row * 128 + slot * 16);
      }
#pragma unroll
      for (int n = 0; n < 2; ++n) {
        int row = wc * 32 + n * 16 + lm;
        int slot = (kk * 4 + lk) ^ (row & 7);
        bfr[n] = *(const bf16x8*)(BsB + row * 128 + slot * 16);
      }
#pragma unroll
      for (int m = 0; m < 2; ++m)
#pragma unroll
        for (int n = 0; n < 2; ++n)
          acc[m][n] = __builtin_amdgcn_mfma_f32_16x16x32_bf16(af[m], bfr[n],
                                                              acc[m][n], 0, 0, 0);
    }
    __syncthreads();  // protect LDS before next stage
  }

  // C/D layout: col = lane&15, row = (lane>>4)*4 + reg
#pragma unroll
  for (int m = 0; m < 2; ++m) {
    int r = row0 + wr * 32 + m * 16 + lk * 4;
#pragma unroll
    for (int n = 0; n < 2; ++n) {
      int c = col0 + wc * 32 + n * 16 + lm;
#pragma unroll
      for (int q = 0; q < 4; ++q) {
        C[(size_t)(r + q) * E_DIM + c] = acc[m][n][q];
      }
    }
  }
}

extern "C" void kernel_launch(void* const* d_in, const int* in_sizes, int n_in,
                              void* d_out, int out_size, void* d_ws, size_t ws_size,
                              hipStream_t stream) {
  const float* x = (const float*)d_in[0];
  const float* W = (const float*)d_in[1];
  const float* w_elem = (const float*)d_in[2];
  const int* perm = (const int*)d_in[3];
  const int* segid = (const int*)d_in[4];
  const int* agg = (const int*)d_in[5];
  float* out = (float*)d_out;

  char* ws = (char*)d_ws;
  unsigned short* y = (unsigned short*)ws;  // B*G bf16 = 16 MB
  unsigned short* Wb =
      (unsigned short*)(ws + (size_t)B_DIM * G_DIM * 2);  // E*G bf16 = 8 MB
  unsigned short* pcol =
      (unsigned short*)(ws + (size_t)B_DIM * G_DIM * 2 + (size_t)E_DIM * G_DIM * 2);
  float* cm_s = (float*)((char*)pcol + (size_t)S_DIM * 2);

  hipLaunchKernelGGL(setup_meta, dim3(S_DIM / 256), dim3(256), 0, stream,
                     w_elem, perm, segid, agg, pcol, cm_s);
  hipLaunchKernelGGL(conv_w, dim3((E_DIM * G_DIM / 4) / 256), dim3(256), 0,
                     stream, W, Wb);
  hipLaunchKernelGGL(seg_reduce, dim3(B_DIM), dim3(1024), 0, stream, x, pcol,
                     cm_s, segid, agg, y);
  hipLaunchKernelGGL(gemm_bt, dim3(E_DIM / 64, B_DIM / 64), dim3(256), 0,
                     stream, y, Wb, out);
}

// Round 5
// 147.654 us; speedup vs baseline: 2.6799x; 1.5201x over previous
//
#include <hip/hip_runtime.h>
#include <hip/hip_bf16.h>

#define B_DIM 2048
#define S_DIM 32768
#define G_DIM 4096
#define E_DIM 1024

typedef __bf16 bf16x8 __attribute__((ext_vector_type(8)));
typedef float f32x4 __attribute__((ext_vector_type(4)));
typedef unsigned short ushort8 __attribute__((ext_vector_type(8)));

__device__ __forceinline__ unsigned short f2bf(float f) {
  unsigned int u = __builtin_bit_cast(unsigned int, f);
  u += 0x7FFFu + ((u >> 16) & 1u);   // round-to-nearest-even (no NaN inputs here)
  return (unsigned short)(u >> 16);
}

__device__ __forceinline__ void async16(void* lds, const void* g) {
  __builtin_amdgcn_global_load_lds(
      (const __attribute__((address_space(1))) unsigned int*)g,
      (__attribute__((address_space(3))) unsigned int*)lds, 16, 0, 0);
}

// Non-returning LDS float atomic add (ds_add_f32). Invisible to the
// compiler's waitcnt model: must be drained with an explicit
// s_waitcnt lgkmcnt(0) before any barrier that readers wait on.
__device__ __forceinline__ void lds_add(float* p, float v) {
  unsigned off = (unsigned)(size_t)(__attribute__((address_space(3))) float*)p;
  asm volatile("ds_add_f32 %0, %1" :: "v"(off), "v"(v));
}

// ---------------- setup: s-ordered packed meta (no scatter) -----------------
// meta1[s] = perm[s] (15b) | orflag (bit15) | bf16(cm) (bits16-31)
//   cm: a==0 -> 1, a==2 -> w_elem[s], a==1 -> 0 (indicator handled via flag)
// meta2[s] = segid[s] (fits u16: G=4096)
__global__ __launch_bounds__(256) void setup_meta(
    const float* __restrict__ w_elem, const int* __restrict__ perm,
    const int* __restrict__ segid, const int* __restrict__ agg,
    unsigned* __restrict__ meta1, unsigned short* __restrict__ meta2) {
  int s = blockIdx.x * 256 + threadIdx.x;
  if (s >= S_DIM) return;
  int g = segid[s];
  int a = agg[g];
  float cm = (a == 0) ? 1.0f : (a == 2 ? w_elem[s] : 0.0f);
  meta1[s] = (unsigned)perm[s] | (a == 1 ? 0x8000u : 0u) |
             ((unsigned)f2bf(cm) << 16);
  meta2[s] = (unsigned short)g;
}

// ---------------- W (f32, [E][G]) -> bf16 ----------------
__global__ __launch_bounds__(256) void conv_w(const float* __restrict__ W,
                                              unsigned short* __restrict__ Wb) {
  size_t i = ((size_t)blockIdx.x * 256 + threadIdx.x) * 4;
  float4 v = *reinterpret_cast<const float4*>(W + i);
  ushort4 o;
  o.x = f2bf(v.x);
  o.y = f2bf(v.y);
  o.z = f2bf(v.z);
  o.w = f2bf(v.w);
  *reinterpret_cast<ushort4*>(Wb + i) = o;
}

// ---------------- stage 1: row-in-LDS (bf16) segment reduce, run-combined --
// One block per row b, 1024 threads, 80 KB LDS -> 2 blocks/CU so staging and
// metadata loads of one block overlap the gather walk of the other.
// Each thread walks 32 consecutive s-positions (segment_ids sorted =>
// contiguous runs, avg len 8), combines runs in-register, flushes once per
// run: plain ds_write for interior (exclusively-owned) runs, ds_add_f32 for
// the <=2 boundary runs.
__global__ __launch_bounds__(1024, 8) void seg_reduce(
    const float* __restrict__ x, const unsigned* __restrict__ meta1,
    const unsigned short* __restrict__ meta2, const int* __restrict__ agg,
    unsigned short* __restrict__ y) {
  __shared__ unsigned short xrow[S_DIM];  // 64 KB (bf16)
  __shared__ float acc[G_DIM];            // 16 KB
  const int t = threadIdx.x;
  const int b = blockIdx.x;

#pragma unroll
  for (int i = 0; i < G_DIM / 1024; ++i) acc[t + i * 1024] = 0.0f;

  // stage full row as bf16: coalesced float4 load -> cvt -> 8B ds_write
  const float4* xg = reinterpret_cast<const float4*>(x + (size_t)b * S_DIM);
  ushort4* xb = reinterpret_cast<ushort4*>(xrow);
#pragma unroll
  for (int i = 0; i < S_DIM / 4 / 1024; ++i) {
    float4 v = xg[i * 1024 + t];
    ushort4 h;
    h.x = f2bf(v.x);
    h.y = f2bf(v.y);
    h.z = f2bf(v.z);
    h.w = f2bf(v.w);
    xb[i * 1024 + t] = h;
  }
  __syncthreads();

  const int s0 = t * 32;
  float sum = 0.0f;
  int gprev = meta2[s0];
  int nflush = 0;

#pragma unroll
  for (int c = 0; c < 4; ++c) {
    int sb = s0 + c * 8;
    uint4 m1a = *reinterpret_cast<const uint4*>(meta1 + sb);
    uint4 m1b = *reinterpret_cast<const uint4*>(meta1 + sb + 4);
    ushort8 m2v = *reinterpret_cast<const ushort8*>(meta2 + sb);
    unsigned m1[8] = {m1a.x, m1a.y, m1a.z, m1a.w, m1b.x, m1b.y, m1b.z, m1b.w};
    float xv[8];
#pragma unroll
    for (int j = 0; j < 8; ++j)
      xv[j] = __builtin_bit_cast(float, (unsigned)xrow[m1[j] & 0x7FFF] << 16);
#pragma unroll
    for (int j = 0; j < 8; ++j) {
      float cm = __builtin_bit_cast(float, m1[j] & 0xFFFF0000u);
      float v = (m1[j] & 0x8000u) ? (xv[j] != 0.0f ? 1.0f : 0.0f)
                                  : xv[j] * cm;
      int g = m2v[j];
      if (g != gprev) {
        if (nflush == 0) {
          lds_add(&acc[gprev], sum);  // first run may extend into prev thread
        } else {
          acc[gprev] = sum;  // interior run: exclusively mine
        }
        ++nflush;
        sum = 0.0f;
        gprev = g;
      }
      sum += v;
    }
  }
  lds_add(&acc[gprev], sum);  // last run may extend into next thread

  // Drain asm ds_adds (invisible to compiler waitcnt model) before barrier.
  asm volatile("s_waitcnt lgkmcnt(0)" ::: "memory");
  __syncthreads();

#pragma unroll
  for (int i = 0; i < G_DIM / 1024; ++i) {
    int g = t + i * 1024;
    float v = acc[g];
    if (agg[g] == 1) v = (v > 0.0f) ? 1.0f : 0.0f;  // acc holds nnz count
    v = fmaxf(v, 0.0f);                              // relu
    y[(size_t)b * G_DIM + g] = f2bf(v);
  }
}

// ---------------- stage 2: out[b,e] = sum_g yr[b,g] * W[e,g]  (bf16 MFMA) --
__global__ __launch_bounds__(256) void gemm_bt(
    const unsigned short* __restrict__ A,   // y bf16 [B_DIM][G_DIM]
    const unsigned short* __restrict__ Bw,  // W bf16 [E_DIM][G_DIM]
    float* __restrict__ C) {                // out f32 [B_DIM][E_DIM]
  __shared__ __align__(16) unsigned short As[64 * 64];  // 8 KB
  __shared__ __align__(16) unsigned short Bs[64 * 64];  // 8 KB
  const int t = threadIdx.x;
  const int lane = t & 63;
  const int wid = t >> 6;
  const int wr = wid >> 1;  // wave row (M)
  const int wc = wid & 1;   // wave col (N)
  const int row0 = blockIdx.y * 64;
  const int col0 = blockIdx.x * 64;

  // staging: thread t covers LDS byte t*16 -> (row=t>>3, slot=t&7)
  const int r_ = t >> 3;  // 0..31
  const int s_ = t & 7;
  const int ksw = (s_ ^ (r_ & 7)) * 8;  // inverse-swizzled k offset (elements)
  const unsigned short* Ag0 = A + (size_t)(row0 + r_) * G_DIM + ksw;
  const unsigned short* Ag1 = A + (size_t)(row0 + r_ + 32) * G_DIM + ksw;
  const unsigned short* Bg0 = Bw + (size_t)(col0 + r_) * G_DIM + ksw;
  const unsigned short* Bg1 = Bw + (size_t)(col0 + r_ + 32) * G_DIM + ksw;

  char* AsB = (char*)As;
  char* BsB = (char*)Bs;
  char* dA0 = AsB + wid * 1024;          // wave-uniform LDS dst bases
  char* dA1 = AsB + 4096 + wid * 1024;
  char* dB0 = BsB + wid * 1024;
  char* dB1 = BsB + 4096 + wid * 1024;

  const int lm = lane & 15;
  const int lk = lane >> 4;  // 0..3

  f32x4 acc[2][2] = {};

  for (int kt = 0; kt < G_DIM; kt += 64) {
    async16(dA0, Ag0 + kt);
    async16(dA1, Ag1 + kt);
    async16(dB0, Bg0 + kt);
    async16(dB1, Bg1 + kt);
    __syncthreads();  // drains vmcnt before barrier
#pragma unroll
    for (int kk = 0; kk < 2; ++kk) {
      bf16x8 af[2], bfr[2];
#pragma unroll
      for (int m = 0; m < 2; ++m) {
        int row = wr * 32 + m * 16 + lm;
        int slot = (kk * 4 + lk) ^ (row & 7);
        af[m] = *(const bf16x8*)(AsB + row * 128 + slot * 16);
      }
#pragma unroll
      for (int n = 0; n < 2; ++n) {
        int row = wc * 32 + n * 16 + lm;
        int slot = (kk * 4 + lk) ^ (row & 7);
        bfr[n] = *(const bf16x8*)(BsB + row * 128 + slot * 16);
      }
#pragma unroll
      for (int m = 0; m < 2; ++m)
#pragma unroll
        for (int n = 0; n < 2; ++n)
          acc[m][n] = __builtin_amdgcn_mfma_f32_16x16x32_bf16(af[m], bfr[n],
                                                              acc[m][n], 0, 0, 0);
    }
    __syncthreads();  // protect LDS before next stage
  }

  // C/D layout: col = lane&15, row = (lane>>4)*4 + reg
#pragma unroll
  for (int m = 0; m < 2; ++m) {
    int r = row0 + wr * 32 + m * 16 + lk * 4;
#pragma unroll
    for (int n = 0; n < 2; ++n) {
      int c = col0 + wc * 32 + n * 16 + lm;
#pragma unroll
      for (int q = 0; q < 4; ++q) {
        C[(size_t)(r + q) * E_DIM + c] = acc[m][n][q];
      }
    }
  }
}

extern "C" void kernel_launch(void* const* d_in, const int* in_sizes, int n_in,
                              void* d_out, int out_size, void* d_ws, size_t ws_size,
                              hipStream_t stream) {
  const float* x = (const float*)d_in[0];
  const float* W = (const float*)d_in[1];
  const float* w_elem = (const float*)d_in[2];
  const int* perm = (const int*)d_in[3];
  const int* segid = (const int*)d_in[4];
  const int* agg = (const int*)d_in[5];
  float* out = (float*)d_out;

  char* ws = (char*)d_ws;
  unsigned short* y = (unsigned short*)ws;  // B*G bf16 = 16 MB
  unsigned short* Wb =
      (unsigned short*)(ws + (size_t)B_DIM * G_DIM * 2);  // E*G bf16 = 8 MB
  unsigned* meta1 =
      (unsigned*)(ws + (size_t)B_DIM * G_DIM * 2 + (size_t)E_DIM * G_DIM * 2);
  unsigned short* meta2 = (unsigned short*)((char*)meta1 + (size_t)S_DIM * 4);

  hipLaunchKernelGGL(setup_meta, dim3(S_DIM / 256), dim3(256), 0, stream,
                     w_elem, perm, segid, agg, meta1, meta2);
  hipLaunchKernelGGL(conv_w, dim3((E_DIM * G_DIM / 4) / 256), dim3(256), 0,
                     stream, W, Wb);
  hipLaunchKernelGGL(seg_reduce, dim3(B_DIM), dim3(1024), 0, stream, x, meta1,
                     meta2, agg, y);
  hipLaunchKernelGGL(gemm_bt, dim3(E_DIM / 64, B_DIM / 64), dim3(256), 0,
                     stream, y, Wb, out);
}

// Round 6
// 137.123 us; speedup vs baseline: 2.8857x; 1.0768x over previous
//
#include <hip/hip_runtime.h>
#include <hip/hip_bf16.h>

#define B_DIM 2048
#define S_DIM 32768
#define G_DIM 4096
#define E_DIM 1024

typedef __bf16 bf16x8 __attribute__((ext_vector_type(8)));
typedef __bf16 bf16x4 __attribute__((ext_vector_type(4)));
typedef float f32x4 __attribute__((ext_vector_type(4)));
typedef unsigned short ushort8 __attribute__((ext_vector_type(8)));

__device__ __forceinline__ unsigned short f2bf(float f) {
  unsigned int u = __builtin_bit_cast(unsigned int, f);
  u += 0x7FFFu + ((u >> 16) & 1u);   // round-to-nearest-even (no NaN inputs here)
  return (unsigned short)(u >> 16);
}

__device__ __forceinline__ void async16(void* lds, const void* g) {
  __builtin_amdgcn_global_load_lds(
      (const __attribute__((address_space(1))) unsigned int*)g,
      (__attribute__((address_space(3))) unsigned int*)lds, 16, 0, 0);
}

// Non-returning LDS float atomic add (ds_add_f32). Invisible to the
// compiler's waitcnt model: must be drained with an explicit
// s_waitcnt lgkmcnt(0) before any barrier that readers wait on.
__device__ __forceinline__ void lds_add(float* p, float v) {
  unsigned off = (unsigned)(size_t)(__attribute__((address_space(3))) float*)p;
  asm volatile("ds_add_f32 %0, %1" :: "v"(off), "v"(v));
}

// ---------------- setup A: per-element packed meta --------------------------
// meta1[s] = perm[s] (15b) | orflag (bit15) | bf16(cm) (bits16-31)
__global__ __launch_bounds__(256) void setup_meta(
    const float* __restrict__ w_elem, const int* __restrict__ perm,
    const int* __restrict__ segid, const int* __restrict__ agg,
    unsigned* __restrict__ meta1) {
  int s = blockIdx.x * 256 + threadIdx.x;
  if (s >= S_DIM) return;
  int g = segid[s];
  int a = agg[g];
  float cm = (a == 0) ? 1.0f : (a == 2 ? w_elem[s] : 0.0f);
  meta1[s] = (unsigned)perm[s] | (a == 1 ? 0x8000u : 0u) |
             ((unsigned)f2bf(cm) << 16);
}

// ---------------- setup B: per-32-window run-head mask + first group -------
// segment_ids sorted ascending => group id increments by exactly 1 at each
// run head. metaH[t] bit j = (segid[t*32+j] != segid[t*32+j-1]); s==0 -> 1.
// metaG[t] = segid[t*32].
__global__ __launch_bounds__(256) void setup_runs(
    const int* __restrict__ segid, unsigned* __restrict__ metaH,
    unsigned short* __restrict__ metaG) {
  int t = blockIdx.x * 256 + threadIdx.x;
  if (t >= S_DIM / 32) return;
  int s0 = t * 32;
  int prev = (s0 == 0) ? -1 : segid[s0 - 1];
  unsigned m = 0;
#pragma unroll
  for (int c = 0; c < 8; ++c) {
    int4 gw = *reinterpret_cast<const int4*>(segid + s0 + c * 4);
    if (gw.x != prev) m |= 1u << (c * 4 + 0);
    if (gw.y != gw.x) m |= 1u << (c * 4 + 1);
    if (gw.z != gw.y) m |= 1u << (c * 4 + 2);
    if (gw.w != gw.z) m |= 1u << (c * 4 + 3);
    prev = gw.w;
  }
  metaH[t] = m;
  metaG[t] = (unsigned short)segid[s0];
}

// ---------------- W (f32, [E][G]) -> bf16 ----------------
__global__ __launch_bounds__(256) void conv_w(const float* __restrict__ W,
                                              unsigned short* __restrict__ Wb) {
  size_t i = ((size_t)blockIdx.x * 256 + threadIdx.x) * 4;
  float4 v = *reinterpret_cast<const float4*>(W + i);
  ushort4 o;
  o.x = f2bf(v.x);
  o.y = f2bf(v.y);
  o.z = f2bf(v.z);
  o.w = f2bf(v.w);
  *reinterpret_cast<ushort4*>(Wb + i) = o;
}

// ---------------- stage 1: row-in-LDS (bf16) segment reduce, run-combined --
// One block per row b, 1024 threads, 80 KB LDS -> 2 blocks/CU. Each thread
// walks 32 consecutive s-positions; group id tracked by ++g at run heads
// (metaH bitmask), no per-element segid loads. Interior runs flush with a
// plain ds_write (exclusive owner); boundary runs with ds_add_f32.
__global__ __launch_bounds__(1024, 8) void seg_reduce(
    const float* __restrict__ x, const unsigned* __restrict__ meta1,
    const unsigned* __restrict__ metaH, const unsigned short* __restrict__ metaG,
    const int* __restrict__ agg, unsigned short* __restrict__ y) {
  __shared__ unsigned short xrow[S_DIM];  // 64 KB (bf16)
  __shared__ float acc[G_DIM];            // 16 KB
  const int t = threadIdx.x;
  const int b = blockIdx.x;

#pragma unroll
  for (int i = 0; i < G_DIM / 1024; ++i) acc[t + i * 1024] = 0.0f;

  // stage full row as bf16: coalesced float4 load -> packed cvt -> 8B ds_write
  const float4* xg = reinterpret_cast<const float4*>(x + (size_t)b * S_DIM);
#pragma unroll
  for (int i = 0; i < S_DIM / 4 / 1024; ++i) {
    float4 v = xg[i * 1024 + t];
    bf16x4 h;
    h.x = (__bf16)v.x;
    h.y = (__bf16)v.y;
    h.z = (__bf16)v.z;
    h.w = (__bf16)v.w;
    *reinterpret_cast<bf16x4*>(&xrow[(i * 1024 + t) * 4]) = h;
  }
  __syncthreads();

  const int s0 = t * 32;
  const unsigned mrun = metaH[t];
  const bool firstPlain = (mrun & 1u) != 0;  // first run starts at s0
  int g = metaG[t];
  float sum = 0.0f;
  int nflush = 0;

  for (int h = 0; h < 2; ++h) {  // two halves of 16 elems
    const int sb = s0 + h * 16;
    uint4 ma = *reinterpret_cast<const uint4*>(meta1 + sb);
    uint4 mb = *reinterpret_cast<const uint4*>(meta1 + sb + 4);
    uint4 mc = *reinterpret_cast<const uint4*>(meta1 + sb + 8);
    uint4 md = *reinterpret_cast<const uint4*>(meta1 + sb + 12);
    unsigned m[16] = {ma.x, ma.y, ma.z, ma.w, mb.x, mb.y, mb.z, mb.w,
                      mc.x, mc.y, mc.z, mc.w, md.x, md.y, md.z, md.w};
    unsigned short xu[16];
#pragma unroll
    for (int j = 0; j < 16; ++j) xu[j] = xrow[m[j] & 0x7FFF];
    const unsigned mh = mrun >> (h * 16);
#pragma unroll
    for (int j = 0; j < 16; ++j) {
      if (h + j > 0 && (mh & (1u << j))) {  // run head: flush previous run
        if (nflush == 0 && !firstPlain) {
          lds_add(&acc[g], sum);  // first run extends into prev thread
        } else {
          acc[g] = sum;  // exclusively-owned run
        }
        ++nflush;
        sum = 0.0f;
        ++g;
      }
      float xv = __builtin_bit_cast(float, (unsigned)xu[j] << 16);
      float cm = __builtin_bit_cast(float, m[j] & 0xFFFF0000u);
      float v = (m[j] & 0x8000u) ? (xu[j] ? 1.0f : 0.0f) : xv * cm;
      sum += v;
    }
  }
  lds_add(&acc[g], sum);  // last run may extend into next thread

  // Drain asm ds_adds (invisible to compiler waitcnt model) before barrier.
  asm volatile("s_waitcnt lgkmcnt(0)" ::: "memory");
  __syncthreads();

#pragma unroll
  for (int i = 0; i < G_DIM / 1024; ++i) {
    int g2 = t + i * 1024;
    float v = acc[g2];
    if (agg[g2] == 1) v = (v > 0.0f) ? 1.0f : 0.0f;  // acc holds nnz count
    v = fmaxf(v, 0.0f);                               // relu
    y[(size_t)b * G_DIM + g2] = f2bf(v);
  }
}

// ---------------- stage 2: out[b,e] = sum_g yr[b,g] * W[e,g]  (bf16 MFMA) --
__global__ __launch_bounds__(256) void gemm_bt(
    const unsigned short* __restrict__ A,   // y bf16 [B_DIM][G_DIM]
    const unsigned short* __restrict__ Bw,  // W bf16 [E_DIM][G_DIM]
    float* __restrict__ C) {                // out f32 [B_DIM][E_DIM]
  __shared__ __align__(16) unsigned short As[64 * 64];  // 8 KB
  __shared__ __align__(16) unsigned short Bs[64 * 64];  // 8 KB
  const int t = threadIdx.x;
  const int lane = t & 63;
  const int wid = t >> 6;
  const int wr = wid >> 1;  // wave row (M)
  const int wc = wid & 1;   // wave col (N)
  const int row0 = blockIdx.y * 64;
  const int col0 = blockIdx.x * 64;

  // staging: thread t covers LDS byte t*16 -> (row=t>>3, slot=t&7)
  const int r_ = t >> 3;  // 0..31
  const int s_ = t & 7;
  const int ksw = (s_ ^ (r_ & 7)) * 8;  // inverse-swizzled k offset (elements)
  const unsigned short* Ag0 = A + (size_t)(row0 + r_) * G_DIM + ksw;
  const unsigned short* Ag1 = A + (size_t)(row0 + r_ + 32) * G_DIM + ksw;
  const unsigned short* Bg0 = Bw + (size_t)(col0 + r_) * G_DIM + ksw;
  const unsigned short* Bg1 = Bw + (size_t)(col0 + r_ + 32) * G_DIM + ksw;

  char* AsB = (char*)As;
  char* BsB = (char*)Bs;
  char* dA0 = AsB + wid * 1024;          // wave-uniform LDS dst bases
  char* dA1 = AsB + 4096 + wid * 1024;
  char* dB0 = BsB + wid * 1024;
  char* dB1 = BsB + 4096 + wid * 1024;

  const int lm = lane & 15;
  const int lk = lane >> 4;  // 0..3

  f32x4 acc[2][2] = {};

  for (int kt = 0; kt < G_DIM; kt += 64) {
    async16(dA0, Ag0 + kt);
    async16(dA1, Ag1 + kt);
    async16(dB0, Bg0 + kt);
    async16(dB1, Bg1 + kt);
    __syncthreads();  // drains vmcnt before barrier
#pragma unroll
    for (int kk = 0; kk < 2; ++kk) {
      bf16x8 af[2], bfr[2];
#pragma unroll
      for (int m = 0; m < 2; ++m) {
        int row = wr * 32 + m * 16 + lm;
        int slot = (kk * 4 + lk) ^ (row & 7);
        af[m] = *(const bf16x8*)(AsB + row * 128 + slot * 16);
      }
#pragma unroll
      for (int n = 0; n < 2; ++n) {
        int row = wc * 32 + n * 16 + lm;
        int slot = (kk * 4 + lk) ^ (row & 7);
        bfr[n] = *(const bf16x8*)(BsB + row * 128 + slot * 16);
      }
#pragma unroll
      for (int m = 0; m < 2; ++m)
#pragma unroll
        for (int n = 0; n < 2; ++n)
          acc[m][n] = __builtin_amdgcn_mfma_f32_16x16x32_bf16(af[m], bfr[n],
                                                              acc[m][n], 0, 0, 0);
    }
    __syncthreads();  // protect LDS before next stage
  }

  // C/D layout: col = lane&15, row = (lane>>4)*4 + reg
#pragma unroll
  for (int m = 0; m < 2; ++m) {
    int r = row0 + wr * 32 + m * 16 + lk * 4;
#pragma unroll
    for (int n = 0; n < 2; ++n) {
      int c = col0 + wc * 32 + n * 16 + lm;
#pragma unroll
      for (int q = 0; q < 4; ++q) {
        C[(size_t)(r + q) * E_DIM + c] = acc[m][n][q];
      }
    }
  }
}

extern "C" void kernel_launch(void* const* d_in, const int* in_sizes, int n_in,
                              void* d_out, int out_size, void* d_ws, size_t ws_size,
                              hipStream_t stream) {
  const float* x = (const float*)d_in[0];
  const float* W = (const float*)d_in[1];
  const float* w_elem = (const float*)d_in[2];
  const int* perm = (const int*)d_in[3];
  const int* segid = (const int*)d_in[4];
  const int* agg = (const int*)d_in[5];
  float* out = (float*)d_out;

  char* ws = (char*)d_ws;
  unsigned short* y = (unsigned short*)ws;  // B*G bf16 = 16 MB
  unsigned short* Wb =
      (unsigned short*)(ws + (size_t)B_DIM * G_DIM * 2);  // E*G bf16 = 8 MB
  unsigned* meta1 =
      (unsigned*)(ws + (size_t)B_DIM * G_DIM * 2 + (size_t)E_DIM * G_DIM * 2);
  unsigned* metaH = (unsigned*)((char*)meta1 + (size_t)S_DIM * 4);
  unsigned short* metaG = (unsigned short*)((char*)metaH + (S_DIM / 32) * 4);

  hipLaunchKernelGGL(setup_meta, dim3(S_DIM / 256), dim3(256), 0, stream,
                     w_elem, perm, segid, agg, meta1);
  hipLaunchKernelGGL(setup_runs, dim3((S_DIM / 32) / 256), dim3(256), 0,
                     stream, segid, metaH, metaG);
  hipLaunchKernelGGL(conv_w, dim3((E_DIM * G_DIM / 4) / 256), dim3(256), 0,
                     stream, W, Wb);
  hipLaunchKernelGGL(seg_reduce, dim3(B_DIM), dim3(1024), 0, stream, x, meta1,
                     metaH, metaG, agg, y);
  hipLaunchKernelGGL(gemm_bt, dim3(E_DIM / 64, B_DIM / 64), dim3(256), 0,
                     stream, y, Wb, out);
}